// Round 16
// baseline (338.797 us; speedup 1.0000x reference)
//
#include <hip/hip_runtime.h>
#include <cstdint>
#include <cstddef>

typedef __attribute__((ext_vector_type(4))) float f32x4;
typedef __attribute__((ext_vector_type(8))) short bf16x8;      // MFMA operand (8 bf16)
typedef __attribute__((ext_vector_type(8))) unsigned short u16x8;
typedef __attribute__((ext_vector_type(4))) float float4v;
typedef __attribute__((ext_vector_type(2))) unsigned long long u64x2;
typedef unsigned long long ull;

// ---- problem dims ----
#define NB   8
#define TIN  200
#define TO1  51
#define VSZ  1024
#define HSZ  512
static constexpr int MJOINT = NB * TIN * TO1;   // 81600
static constexpr int MROWS  = TO1 * NB;         // 408  (rows t*8+n)

// ---- ws layout (bytes) ----
static constexpr size_t B_ENCBF = 0;                           // 1664*512*2
static constexpr size_t B_ENCW  = B_ENCBF + 1664ull*512*2;     // 512*512*2
static constexpr size_t B_DECW  = B_ENCW  + 512ull*512*2;
static constexpr size_t B_OUTW  = B_DECW  + 512ull*512*2;      // 1024*512*2
static constexpr size_t B_WIH   = B_OUTW  + 1024ull*512*2;     // 3*2048*512*2
static constexpr size_t B_WHH   = B_WIH   + 3ull*2048*512*2;
static constexpr size_t B_XTR   = B_WHH   + 3ull*2048*512*2;   // 4*408*512*2 (x0,h1,h2,h3 traces)
static constexpr size_t B_BSUM  = B_XTR   + 4ull*408*512*2;    // 3*2048*4
static constexpr size_t B_FLAGS = B_BSUM  + 3ull*2048*4;       // 96 flags + encdone (x64B)
static constexpr size_t B_ENCP  = B_FLAGS + 8192;              // 1664*512*4
static constexpr size_t B_DECP  = B_ENCP  + 1664ull*512*4;     // 512*512*4 (unused now)
static constexpr size_t B_ABUF  = B_DECP  + 512ull*512*4;      // 81664*512*2

// ---- helpers ----
__device__ __forceinline__ unsigned short f2bf(float f) {
  union { float f; unsigned u; } v; v.f = f;
  unsigned r = v.u + 0x7FFFu + ((v.u >> 16) & 1u);
  return (unsigned short)(r >> 16);
}
__device__ __forceinline__ float fast_tanh(float x) {
  float t = __expf(2.0f * x);          // inf-safe: x>>0 -> 1, x<<0 -> -1
  return 1.0f - 2.0f / (t + 1.0f);
}
__device__ __forceinline__ float fast_sig(float x) {
  return 1.0f / (1.0f + __expf(-x));
}
__device__ __forceinline__ void gll16(const void* g, void* l) {
  __builtin_amdgcn_global_load_lds(
      (const __attribute__((address_space(1))) unsigned int*)g,
      (__attribute__((address_space(3))) unsigned int*)l, 16, 0, 0);
}
__device__ __forceinline__ void cvt8(const float* s, unsigned short* d) {
  const float4v* sp = (const float4v*)s;
  float4v x = sp[0], y = sp[1];
  u16x8 o;
  o[0]=f2bf(x[0]); o[1]=f2bf(x[1]); o[2]=f2bf(x[2]); o[3]=f2bf(x[3]);
  o[4]=f2bf(y[0]); o[5]=f2bf(y[1]); o[6]=f2bf(y[2]); o[7]=f2bf(y[3]);
  *(u16x8*)d = o;
}
#define ALOAD(P)     __hip_atomic_load((P), __ATOMIC_RELAXED, __HIP_MEMORY_SCOPE_AGENT)
#define ASTORE(P, V) __hip_atomic_store((P), (V), __ATOMIC_RELAXED, __HIP_MEMORY_SCOPE_AGENT)

// ---------------- fused prep: fp32->bf16 cvt + flag zero + bsum + embed ----------------
static constexpr int N_ENC  = 102400;           // 8*200*512/8
static constexpr int N_ENCW = 32768;
static constexpr int N_DECW = 32768;
static constexpr int N_OUTW = 65536;
static constexpr int N_WIH  = 393216;
static constexpr int P0 = N_ENC, P1 = P0+N_ENCW, P2 = P1+N_DECW, P3 = P2+N_OUTW,
                     P4 = P3+N_WIH;   // total 1019904 (=3984*256)
// grid: [0,3984) cvt | [3984,4086) embed | [4086,4089) bsum

__global__ __launch_bounds__(256) void prep_all(const float* __restrict__ enc,
                                                const float* __restrict__ encw,
                                                const float* __restrict__ decw,
                                                const float* __restrict__ outw,
                                                const float* __restrict__ wih,
                                                const float* __restrict__ whh,
                                                const float* __restrict__ emb,
                                                const int* __restrict__ tgt,
                                                const float* __restrict__ bih,
                                                const float* __restrict__ bhh,
                                                unsigned short* __restrict__ d_enc,
                                                unsigned short* __restrict__ d_encw,
                                                unsigned short* __restrict__ d_decw,
                                                unsigned short* __restrict__ d_outw,
                                                unsigned short* __restrict__ d_wih,
                                                unsigned short* __restrict__ d_whh,
                                                unsigned short* __restrict__ x0,
                                                float* __restrict__ bsum,
                                                int* __restrict__ flags) {
  if (blockIdx.x == 0 && threadIdx.x < 97) flags[threadIdx.x * 16] = 0;  // 96 rnn + encdone
  if (blockIdx.x >= 4086) {                    // bsum: 6144 floats, 8/thread
    int i = (blockIdx.x - 4086) * 2048 + threadIdx.x * 8;
#pragma unroll
    for (int k = 0; k < 8; ++k) bsum[i + k] = bih[i + k] + bhh[i + k];
    return;
  }
  if (blockIdx.x >= 3984) {                    // embed: 408*64 threads
    int idx = (blockIdx.x - 3984) * 256 + threadIdx.x;
    if (idx >= MROWS * 64) return;
    int m = idx >> 6, kc = (idx & 63) * 8;
    int t = m >> 3, n = m & 7;
    int v = tgt[n * TO1 + t];
    cvt8(emb + (size_t)v * 512 + kc, x0 + (size_t)m * 512 + kc);
    return;
  }
  int i = blockIdx.x * 256 + threadIdx.x;
  const float* s; unsigned short* d; int rel;
  if      (i < P0) { s = enc;  d = d_enc;  rel = i; }
  else if (i < P1) { s = encw; d = d_encw; rel = i - P0; }
  else if (i < P2) { s = decw; d = d_decw; rel = i - P1; }
  else if (i < P3) { s = outw; d = d_outw; rel = i - P2; }
  else if (i < P4) { s = wih;  d = d_wih;  rel = i - P3; }
  else             { s = whh;  d = d_whh;  rel = i - P4; }
  cvt8(s + (size_t)rel * 8, d + (size_t)rel * 8);
}

// ---------------- joint GEMM: 256x256 tile, 512 thr, BK=32, 64KB LDS ----------------
__global__ __launch_bounds__(512, 2) void gemm256(const unsigned short* __restrict__ A,
                                                  const unsigned short* __restrict__ B,
                                                  float* __restrict__ C,
                                                  int M, int N, int K) {
  __shared__ __align__(16) unsigned short lds[2][2][8192];   // 64 KB
  const int tid = threadIdx.x;
  const int wave = tid >> 6, lane = tid & 63;
  const int lr = lane & 15, lg = lane >> 4;
  const int wr = (wave >> 2) * 128;        // 0 / 128
  const int wc = (wave & 3) * 64;          // 0..192

  const int nwg = gridDim.x * gridDim.y;
  const int id = blockIdx.y * gridDim.x + blockIdx.x;
  const int q = nwg >> 3, r = nwg & 7, xcd = id & 7, rest = id >> 3;
  const int nid = (xcd < r ? xcd * (q + 1) : r * (q + 1) + (xcd - r) * q) + rest;
  const size_t n0 = (size_t)(nid % gridDim.x) * 256;
  const size_t m0 = (size_t)(nid / gridDim.x) * 256;

  f32x4 acc[8][4];
#pragma unroll
  for (int i = 0; i < 8; ++i)
#pragma unroll
    for (int j = 0; j < 4; ++j) acc[i][j] = (f32x4){0.f, 0.f, 0.f, 0.f};

#define STG(bf, kt)                                                                    \
  do {                                                                                 \
    _Pragma("unroll") for (int u = 0; u < 2; ++u) {                                    \
      const int idx = u * 512 + tid;                                                   \
      const int row_ = idx >> 2;                                                       \
      const int ch = (idx & 3) ^ (row_ & 3);                                           \
      gll16(A + (m0 + row_) * (size_t)K + (kt) + ch * 8,                               \
            &lds[bf][0][(u * 512 + wave * 64) * 8]);                                   \
    }                                                                                  \
    _Pragma("unroll") for (int u = 0; u < 2; ++u) {                                    \
      const int idx = u * 512 + tid;                                                   \
      const int row_ = idx >> 2;                                                       \
      const int ch = (idx & 3) ^ (row_ & 3);                                           \
      gll16(B + (n0 + row_) * (size_t)K + (kt) + ch * 8,                               \
            &lds[bf][1][(u * 512 + wave * 64) * 8]);                                   \
    }                                                                                  \
  } while (0)

  const int nt = K >> 5;                   // 16 K-steps
  int cur = 0;
  STG(0, 0);
  for (int t = 0; t < nt; ++t) {
    if (t + 1 < nt) {
      STG(cur ^ 1, (t + 1) * 32);
      asm volatile("s_waitcnt vmcnt(4)" ::: "memory");
    } else {
      asm volatile("s_waitcnt vmcnt(0)" ::: "memory");
    }
    __builtin_amdgcn_s_barrier();
    const unsigned short* As_ = lds[cur][0];
    const unsigned short* Bs_ = lds[cur][1];
    bf16x8 b[4];
#pragma unroll
    for (int j = 0; j < 4; ++j) {
      const int rb = wc + j * 16 + lr;
      b[j] = *(const bf16x8*)&Bs_[rb * 32 + ((lg ^ (rb & 3)) << 3)];
    }
    __builtin_amdgcn_s_setprio(1);
#pragma unroll
    for (int i = 0; i < 8; ++i) {
      const int ra = wr + i * 16 + lr;
      bf16x8 a0 = *(const bf16x8*)&As_[ra * 32 + ((lg ^ (ra & 3)) << 3)];
#pragma unroll
      for (int j = 0; j < 4; ++j)
        acc[i][j] = __builtin_amdgcn_mfma_f32_16x16x32_bf16(a0, b[j], acc[i][j], 0, 0, 0);
    }
    __builtin_amdgcn_s_setprio(0);
    __builtin_amdgcn_s_barrier();
    cur ^= 1;
  }
#undef STG

#pragma unroll
  for (int i = 0; i < 8; ++i) {
#pragma unroll
    for (int q2 = 0; q2 < 4; ++q2) {
      const long m = (long)m0 + wr + i * 16 + lg * 4 + q2;
      if (m < M) {
        float* crow = C + (size_t)m * N + n0 + wc;
#pragma unroll
        for (int j = 0; j < 4; ++j) crow[j * 16 + lr] = acc[i][j][q2];
      }
    }
  }
}

// ---------------- mega kernel: rnn(0-95) + enc-proj(96-147) + joint-prep(148-249) --------
// All 250 blocks co-resident (1/CU) -> internal flag pipelining is dispatch-order safe.
// Cross-block same-kernel data: atomics where a stale local line is possible; PLAIN loads
// where provably no prior plain read cached the line on any XCD (encp after encdone).
__global__ __launch_bounds__(256) void mega_kernel(const unsigned short* __restrict__ wih,
                                                   const unsigned short* __restrict__ whh,
                                                   const float* __restrict__ bsum,
                                                   unsigned short* __restrict__ xtr,
                                                   int* __restrict__ flags,
                                                   const unsigned short* __restrict__ eA,
                                                   const unsigned short* __restrict__ eB,
                                                   float* __restrict__ eC,
                                                   const unsigned short* __restrict__ decw,
                                                   const float* __restrict__ dec_b,
                                                   const float* __restrict__ encp,
                                                   unsigned short* __restrict__ abuf) {
  __shared__ __align__(16) unsigned short w_s[64 * 1024];   // 128 KB (role-dependent alias)
  __shared__ __align__(16) unsigned short x_s[8 * 512];     // 8 KB
  __shared__ __align__(16) unsigned short h_s[8 * 512];     // 8 KB
  __shared__ float gates_s[4][8][16];

  const int tid = threadIdx.x;
  const int wave = tid >> 6, lane = tid & 63;
  const int lr = lane & 15, lg = lane >> 4;
  const int r7 = lr & 7;

  if (blockIdx.x >= 148) {
    // ================= joint-prep workers: dec_p(u,n) + tanh -> abuf =================
    const int wkr = blockIdx.x - 148;          // 0..101
    unsigned short* h3_s = x_s;
    float* decp_row = (float*)w_s;             // 512 floats
    const unsigned short* xtr3 = xtr + 3ull * MROWS * 512;
#pragma unroll 1
    for (int k = 0; k < 4; ++k) {
      const int j = wkr + 102 * k;             // 0..407
      const int u = j >> 3;                    // decoder step
      const int p = j & 7;                     // batch n
      // poll: lanes<32 -> layer-2 flags >= u+1 ; lane 32 -> encdone == 52
      if (wave == 0) {
        for (;;) {
          bool ok = true;
          if (lane < 32) ok = ALOAD(&flags[(64 + lane) * 16]) >= u + 1;
          else if (lane == 32) ok = ALOAD(&flags[96 * 16]) >= 52;
          if (__all(ok)) break;
          __builtin_amdgcn_s_sleep(1);
        }
      }
      __syncthreads();
      // stage h3 rows (u*8..u*8+7) -> swizzled LDS (coherent atomic loads; tiny)
      {
        const int sr2 = tid >> 5, sc2 = tid & 31;
        const ull* ph = (const ull*)(xtr3 + ((size_t)u * 8 + sr2) * 512);
#pragma unroll
        for (int k2 = 0; k2 < 2; ++k2) {
          const int c_ = sc2 + k2 * 32;
          ull v0 = ALOAD(ph + c_ * 2), v1 = ALOAD(ph + c_ * 2 + 1);
          *(u64x2*)&h3_s[sr2 * 512 + ((c_ ^ sr2) << 3)] = (u64x2){v0, v1};
        }
      }
      __syncthreads();
      // dec_p row p: each wave computes 128 cols (8 col-tiles x K=512)
      {
        const int colbase = wave * 128;
#pragma unroll
        for (int ct = 0; ct < 8; ++ct) {
          f32x4 acc = (f32x4){0.f, 0.f, 0.f, 0.f};
          const int col = colbase + ct * 16 + lr;
#pragma unroll
          for (int c16 = 0; c16 < 16; ++c16) {
            const int cc = c16 * 4 + lg;
            bf16x8 av = *(const bf16x8*)&h3_s[r7 * 512 + ((cc ^ r7) << 3)];
            bf16x8 bv = *(const bf16x8*)&decw[(size_t)col * 512 + cc * 8];
            acc = __builtin_amdgcn_mfma_f32_16x16x32_bf16(av, bv, acc, 0, 0, 0);
          }
#pragma unroll
          for (int q2 = 0; q2 < 4; ++q2)
            if (lg * 4 + q2 == p) decp_row[col] = acc[q2] + dec_b[col];
        }
      }
      __syncthreads();
      // tanh(encp[nt] + decp_row) -> abuf[nt*51+u]. PLAIN cached loads of encp:
      // safe because no plain read of encp precedes encdone in this dispatch, and the
      // kernel-launch acquire invalidated stale lines from prior replays -> L2 miss
      // fills from L3 with the enc-proj blocks' written-through data.
      {
        const int tr = tid >> 6;               // 0..3 rows per pass
        const int colc = (lane) * 8;           // 0..504
        for (int pass = 0; pass < 50; ++pass) {
          const int nt = p * 200 + pass * 4 + tr;
          const float4v* pe = (const float4v*)(encp + (size_t)nt * 512 + colc);
          float4v e0 = pe[0], e1 = pe[1];
          u16x8 o;
#pragma unroll
          for (int w2 = 0; w2 < 4; ++w2) {
            o[w2]     = f2bf(fast_tanh(e0[w2] + decp_row[colc + w2]));
            o[4 + w2] = f2bf(fast_tanh(e1[w2] + decp_row[colc + 4 + w2]));
          }
          *(u16x8*)&abuf[((size_t)nt * TO1 + u) * 512 + colc] = o;
        }
      }
      __syncthreads();                          // LDS reuse guard for next job
    }
    return;
  }

  if (blockIdx.x >= 96) {
    // ================= enc-proj GEMM: eC[1664][512] = eA @ eB^T (atomic C) =============
    unsigned short* eld = w_s;
    const int g = blockIdx.x - 96;             // 0..51
    const int wm = (wave >> 1) * 64, wn = (wave & 1) * 64;
    const int xsl = (lg ^ (lr & 3)) << 3;
    const int nwg = 52;
    const int q = nwg >> 3, r = nwg & 7, xcd = g & 7, rest = g >> 3;
    const int nid = (xcd < r ? xcd * (q + 1) : r * (q + 1) + (xcd - r) * q) + rest;
    const size_t n0 = (size_t)(nid & 3) * 128;
    const size_t m0 = (size_t)(nid >> 2) * 128;

    f32x4 acc[4][4];
#pragma unroll
    for (int i = 0; i < 4; ++i)
#pragma unroll
      for (int j = 0; j < 4; ++j) acc[i][j] = (f32x4){0.f, 0.f, 0.f, 0.f};

#define ESTG(bf, kt)                                                                   \
    do {                                                                               \
      _Pragma("unroll") for (int u = 0; u < 2; ++u) {                                  \
        const int s = u * 256 + tid;                                                   \
        const int row_ = s >> 2;                                                       \
        const int ch = (s & 3) ^ (row_ & 3);                                           \
        gll16(eA + (m0 + row_) * 512 + (kt) + ch * 8,                                  \
              &eld[(bf) * 8192 + (u * 256 + wave * 64) * 8]);                          \
      }                                                                                \
      _Pragma("unroll") for (int u = 0; u < 2; ++u) {                                  \
        const int s = u * 256 + tid;                                                   \
        const int row_ = s >> 2;                                                       \
        const int ch = (s & 3) ^ (row_ & 3);                                           \
        gll16(eB + (n0 + row_) * 512 + (kt) + ch * 8,                                  \
              &eld[(bf) * 8192 + 4096 + (u * 256 + wave * 64) * 8]);                   \
      }                                                                                \
    } while (0)

    int cur = 0;
    ESTG(0, 0);
    for (int t = 0; t < 16; ++t) {
      if (t + 1 < 16) {
        ESTG(cur ^ 1, (t + 1) * 32);
        asm volatile("s_waitcnt vmcnt(4)" ::: "memory");
      } else {
        asm volatile("s_waitcnt vmcnt(0)" ::: "memory");
      }
      __builtin_amdgcn_s_barrier();
      const unsigned short* As_ = eld + cur * 8192;
      const unsigned short* Bs_ = As_ + 4096;
      bf16x8 a[4], b[4];
#pragma unroll
      for (int i = 0; i < 4; ++i) a[i] = *(const bf16x8*)&As_[(wm + i * 16 + lr) * 32 + xsl];
#pragma unroll
      for (int j = 0; j < 4; ++j) b[j] = *(const bf16x8*)&Bs_[(wn + j * 16 + lr) * 32 + xsl];
      __builtin_amdgcn_s_setprio(1);
#pragma unroll
      for (int i = 0; i < 4; ++i)
#pragma unroll
        for (int j = 0; j < 4; ++j)
          acc[i][j] = __builtin_amdgcn_mfma_f32_16x16x32_bf16(a[i], b[j], acc[i][j], 0, 0, 0);
      __builtin_amdgcn_s_setprio(0);
      __builtin_amdgcn_s_barrier();
      cur ^= 1;
    }
#undef ESTG

    const int rq = lg * 4;
#pragma unroll
    for (int j = 0; j < 4; ++j) {
      const int col = (int)n0 + wn + j * 16 + lr;
#pragma unroll
      for (int i = 0; i < 4; ++i) {
#pragma unroll
        for (int q2 = 0; q2 < 4; ++q2) {
          const long m = (long)m0 + wm + i * 16 + rq + q2;
          ASTORE(&eC[(size_t)m * 512 + col], acc[i][j][q2]);   // write-through
        }
      }
    }
    asm volatile("s_waitcnt vmcnt(0)" ::: "memory");   // C at coherence point
    __syncthreads();
    if (tid == 0)
      __hip_atomic_fetch_add(&flags[96 * 16], 1, __ATOMIC_RELAXED, __HIP_MEMORY_SCOPE_AGENT);
    return;
  }

  // ================= rnn (blocks 0..95), combined-poll/stage structure =================
  const int l = blockIdx.x >> 5;
  const int b32 = blockIdx.x & 31;
  const int hid0 = b32 << 4;
  const int rw = wave * 16 + lr;

  {
    const int rl = tid >> 2;
    const int qt = tid & 3;
    const size_t R = (size_t)l * 2048 + (size_t)(rl >> 4) * 512 + hid0 + (rl & 15);
    const unsigned short* s0 = wih + R * 512;
    const unsigned short* s1 = whh + R * 512;
#pragma unroll
    for (int i = 0; i < 32; ++i) {
      int c = qt * 32 + i;
      bf16x8 wv = (c < 64) ? *(const bf16x8*)&s0[c * 8] : *(const bf16x8*)&s1[(c - 64) * 8];
      *(bf16x8*)&w_s[rl * 1024 + ((c ^ (rl & 7)) << 3)] = wv;
    }
  }
  const float bias = bsum[(size_t)l * 2048 + (size_t)wave * 512 + hid0 + lr];

  const unsigned short* xin = xtr + (size_t)l * MROWS * 512;
  unsigned short* xout = xtr + (size_t)(l + 1) * MROWS * 512;
  float c_reg = 0.f;
  const int srow = tid >> 5;
  const int sc = tid & 31;
  __syncthreads();

  f32x4 ax0, ax1;

  // ---- prologue: x(0) ----
  if (l > 0) {
    if (wave == 0) {
      for (;;) {
        bool ok_ = true;
        if (lane < 32)
          ok_ = ALOAD(&flags[((l - 1) * 32 + lane) * 16]) >= 1;
        if (__all(ok_)) break;
        __builtin_amdgcn_s_sleep(1);
      }
    }
  }
  __syncthreads();
  {
    const ull* px = (const ull*)(xin + (size_t)srow * 512);
#pragma unroll
    for (int k_ = 0; k_ < 2; ++k_) {
      const int c_ = sc + k_ * 32;
      ull v0 = ALOAD(px + c_ * 2), v1 = ALOAD(px + c_ * 2 + 1);
      *(u64x2*)&x_s[srow * 512 + ((c_ ^ srow) << 3)] = (u64x2){v0, v1};
    }
  }
  __syncthreads();
  ax0 = (f32x4){0.f, 0.f, 0.f, 0.f};
  ax1 = (f32x4){0.f, 0.f, 0.f, 0.f};
#pragma unroll
  for (int c16 = 0; c16 < 16; ++c16) {
    const int cc = c16 * 4 + lg;
    bf16x8 av = *(const bf16x8*)&x_s[r7 * 512 + ((cc ^ r7) << 3)];
    bf16x8 bv = *(const bf16x8*)&w_s[rw * 1024 + ((cc ^ r7) << 3)];
    if (c16 & 1) ax1 = __builtin_amdgcn_mfma_f32_16x16x32_bf16(av, bv, ax1, 0, 0, 0);
    else         ax0 = __builtin_amdgcn_mfma_f32_16x16x32_bf16(av, bv, ax0, 0, 0, 0);
  }

  for (int t = 0; t < TO1; ++t) {
    const bool doH = (t > 0);
    const bool doX = (t + 1 < TO1);
    // ---- combined poll: lanes<32 -> own siblings (h), lanes>=32 -> l-1 (x(t+1)) ----
    if (doH || (doX && l > 0)) {
      if (wave == 0) {
        for (;;) {
          bool ok_ = true;
          if (lane < 32) {
            if (doH) ok_ = ALOAD(&flags[(l * 32 + lane) * 16]) >= t;
          } else {
            if (doX && l > 0)
              ok_ = ALOAD(&flags[((l - 1) * 32 + (lane - 32)) * 16]) >= t + 2;
          }
          if (__all(ok_)) break;
          __builtin_amdgcn_s_sleep(1);
        }
      }
    }
    __syncthreads();   // also protects x_s/h_s reuse (prior compute finished)

    // ---- combined stage: issue ALL atomic loads (h + x) back-to-back -> one RT ----
    {
      ull vh[4], vx[4];
      const ull* ph = (const ull*)(xout + ((size_t)(t - 1) * 8 + srow) * 512);
      const ull* px = (const ull*)(xin + ((size_t)(t + 1) * 8 + srow) * 512);
#pragma unroll
      for (int k_ = 0; k_ < 2; ++k_) {
        const int c_ = sc + k_ * 32;
        if (doH) { vh[2 * k_] = ALOAD(ph + c_ * 2); vh[2 * k_ + 1] = ALOAD(ph + c_ * 2 + 1); }
        if (doX) { vx[2 * k_] = ALOAD(px + c_ * 2); vx[2 * k_ + 1] = ALOAD(px + c_ * 2 + 1); }
      }
#pragma unroll
      for (int k_ = 0; k_ < 2; ++k_) {
        const int c_ = sc + k_ * 32;
        if (doH) *(u64x2*)&h_s[srow * 512 + ((c_ ^ srow) << 3)] = (u64x2){vh[2 * k_], vh[2 * k_ + 1]};
        if (doX) *(u64x2*)&x_s[srow * 512 + ((c_ ^ srow) << 3)] = (u64x2){vx[2 * k_], vx[2 * k_ + 1]};
      }
    }
    __syncthreads();

    // ---- h half (critical): 16 MFMAs on staged h(t-1) ----
    f32x4 acc0 = ax0, acc1 = ax1;
    if (doH) {
#pragma unroll
      for (int c16 = 0; c16 < 16; ++c16) {
        const int cc = c16 * 4 + lg;
        bf16x8 av = *(const bf16x8*)&h_s[r7 * 512 + ((cc ^ r7) << 3)];
        bf16x8 bv = *(const bf16x8*)&w_s[rw * 1024 + (((64 + cc) ^ r7) << 3)];
        if (c16 & 1) acc1 = __builtin_amdgcn_mfma_f32_16x16x32_bf16(av, bv, acc1, 0, 0, 0);
        else         acc0 = __builtin_amdgcn_mfma_f32_16x16x32_bf16(av, bv, acc0, 0, 0, 0);
      }
    }

    // ---- gates -> LDS ----
    {
      f32x4 g = acc0 + acc1;
      const int nb4 = lg * 4;
#pragma unroll
      for (int q2 = 0; q2 < 4; ++q2) {
        int n = nb4 + q2;
        if (n < 8) gates_s[wave][n][lr] = g[q2] + bias;
      }
    }
    __syncthreads();
    if (tid < 128) {
      const int n = tid >> 4, j = tid & 15;
      float gi = gates_s[0][n][j], gf = gates_s[1][n][j];
      float gg = gates_s[2][n][j], go = gates_s[3][n][j];
      c_reg = fast_sig(gf) * c_reg + fast_sig(gi) * fast_tanh(gg);
      float ht = fast_sig(go) * fast_tanh(c_reg);
      float htn = __shfl_down(ht, 1);
      if (!(j & 1)) {
        unsigned pk = (unsigned)f2bf(ht) | ((unsigned)f2bf(htn) << 16);
        ASTORE((unsigned*)(xout + ((size_t)t * 8 + n) * 512 + hid0 + j), pk);
      }
    }
    asm volatile("s_waitcnt vmcnt(0)" ::: "memory");   // h at coherence point
    __syncthreads();                                   // ...for ALL waves
    if (tid == 0)
      ASTORE(&flags[(l * 32 + b32) * 16], t + 1);

    // ---- x half for t+1 (no RT: x_s already staged this step) ----
    if (doX) {
      ax0 = (f32x4){0.f, 0.f, 0.f, 0.f};
      ax1 = (f32x4){0.f, 0.f, 0.f, 0.f};
#pragma unroll
      for (int c16 = 0; c16 < 16; ++c16) {
        const int cc = c16 * 4 + lg;
        bf16x8 av = *(const bf16x8*)&x_s[r7 * 512 + ((cc ^ r7) << 3)];
        bf16x8 bv = *(const bf16x8*)&w_s[rw * 1024 + ((cc ^ r7) << 3)];
        if (c16 & 1) ax1 = __builtin_amdgcn_mfma_f32_16x16x32_bf16(av, bv, ax1, 0, 0, 0);
        else         ax0 = __builtin_amdgcn_mfma_f32_16x16x32_bf16(av, bv, ax0, 0, 0, 0);
      }
    }
  }
}

// ---------------- launch ----------------
extern "C" void kernel_launch(void* const* d_in, const int* in_sizes, int n_in,
                              void* d_out, int out_size, void* d_ws, size_t ws_size,
                              hipStream_t stream) {
  (void)in_sizes; (void)n_in; (void)out_size; (void)ws_size;
  const float* enc_out = (const float*)d_in[0];
  const int*   tgt     = (const int*)d_in[1];
  const float* embed   = (const float*)d_in[2];
  const float* w_ih    = (const float*)d_in[3];
  const float* w_hh    = (const float*)d_in[4];
  const float* b_ih    = (const float*)d_in[5];
  const float* b_hh    = (const float*)d_in[6];
  const float* enc_w   = (const float*)d_in[7];
  const float* dec_w   = (const float*)d_in[8];
  const float* dec_b   = (const float*)d_in[9];
  const float* out_w   = (const float*)d_in[10];

  char* ws = (char*)d_ws;
  unsigned short* enc_bf  = (unsigned short*)(ws + B_ENCBF);
  unsigned short* encw_bf = (unsigned short*)(ws + B_ENCW);
  unsigned short* decw_bf = (unsigned short*)(ws + B_DECW);
  unsigned short* outw_bf = (unsigned short*)(ws + B_OUTW);
  unsigned short* wih_bf  = (unsigned short*)(ws + B_WIH);
  unsigned short* whh_bf  = (unsigned short*)(ws + B_WHH);
  unsigned short* xtr     = (unsigned short*)(ws + B_XTR);
  float* bsum  = (float*)(ws + B_BSUM);
  int*   flags = (int*)(ws + B_FLAGS);
  float* encp  = (float*)(ws + B_ENCP);
  unsigned short* abuf = (unsigned short*)(ws + B_ABUF);
  float* Cout  = (float*)d_out;

  prep_all<<<4089, 256, 0, stream>>>(enc_out, enc_w, dec_w, out_w, w_ih, w_hh,
                                     embed, tgt, b_ih, b_hh,
                                     enc_bf, encw_bf, decw_bf, outw_bf, wih_bf, whh_bf,
                                     xtr, bsum, flags);

  mega_kernel<<<250, 256, 0, stream>>>(wih_bf, whh_bf, bsum, xtr, flags,
                                       enc_bf, encw_bf, encp,
                                       decw_bf, dec_b, encp, abuf);

  gemm256<<<dim3(4, 319), 512, 0, stream>>>(abuf, outw_bf, Cout, MJOINT, VSZ, 512);
}

// Round 17
// 323.194 us; speedup vs baseline: 1.0483x; 1.0483x over previous
//
#include <hip/hip_runtime.h>
#include <cstdint>
#include <cstddef>

typedef __attribute__((ext_vector_type(4))) float f32x4;
typedef __attribute__((ext_vector_type(8))) short bf16x8;      // MFMA operand (8 bf16)
typedef __attribute__((ext_vector_type(8))) unsigned short u16x8;
typedef __attribute__((ext_vector_type(4))) float float4v;
typedef __attribute__((ext_vector_type(2))) unsigned long long u64x2;
typedef unsigned long long ull;

// ---- problem dims ----
#define NB   8
#define TIN  200
#define TO1  51
#define VSZ  1024
#define HSZ  512
static constexpr int MJOINT = NB * TIN * TO1;   // 81600
static constexpr int MROWS  = TO1 * NB;         // 408  (rows t*8+n)

// ---- ws layout (bytes) ----
static constexpr size_t B_ENCBF = 0;                           // 1664*512*2
static constexpr size_t B_ENCW  = B_ENCBF + 1664ull*512*2;     // 512*512*2
static constexpr size_t B_DECW  = B_ENCW  + 512ull*512*2;
static constexpr size_t B_OUTW  = B_DECW  + 512ull*512*2;      // 1024*512*2
static constexpr size_t B_WIH   = B_OUTW  + 1024ull*512*2;     // 3*2048*512*2
static constexpr size_t B_WHH   = B_WIH   + 3ull*2048*512*2;
static constexpr size_t B_XTR   = B_WHH   + 3ull*2048*512*2;   // 4*408*512*2 (x0,h1,h2,h3 traces)
static constexpr size_t B_BSUM  = B_XTR   + 4ull*408*512*2;    // 3*2048*4
static constexpr size_t B_FLAGS = B_BSUM  + 3ull*2048*4;       // 96 flags + encdone (x64B)
static constexpr size_t B_ENCP  = B_FLAGS + 8192;              // 1664*512*4
static constexpr size_t B_DECP  = B_ENCP  + 1664ull*512*4;     // 512*512*4 (unused now)
static constexpr size_t B_ABUF  = B_DECP  + 512ull*512*4;      // 81664*512*2

// ---- helpers ----
__device__ __forceinline__ unsigned short f2bf(float f) {
  union { float f; unsigned u; } v; v.f = f;
  unsigned r = v.u + 0x7FFFu + ((v.u >> 16) & 1u);
  return (unsigned short)(r >> 16);
}
__device__ __forceinline__ float fast_tanh(float x) {
  float t = __expf(2.0f * x);          // inf-safe: x>>0 -> 1, x<<0 -> -1
  return 1.0f - 2.0f / (t + 1.0f);
}
__device__ __forceinline__ float fast_sig(float x) {
  return 1.0f / (1.0f + __expf(-x));
}
__device__ __forceinline__ void gll16(const void* g, void* l) {
  __builtin_amdgcn_global_load_lds(
      (const __attribute__((address_space(1))) unsigned int*)g,
      (__attribute__((address_space(3))) unsigned int*)l, 16, 0, 0);
}
__device__ __forceinline__ void cvt8(const float* s, unsigned short* d) {
  const float4v* sp = (const float4v*)s;
  float4v x = sp[0], y = sp[1];
  u16x8 o;
  o[0]=f2bf(x[0]); o[1]=f2bf(x[1]); o[2]=f2bf(x[2]); o[3]=f2bf(x[3]);
  o[4]=f2bf(y[0]); o[5]=f2bf(y[1]); o[6]=f2bf(y[2]); o[7]=f2bf(y[3]);
  *(u16x8*)d = o;
}
#define ALOAD(P)     __hip_atomic_load((P), __ATOMIC_RELAXED, __HIP_MEMORY_SCOPE_AGENT)
#define ASTORE(P, V) __hip_atomic_store((P), (V), __ATOMIC_RELAXED, __HIP_MEMORY_SCOPE_AGENT)

// ---------------- fused prep: fp32->bf16 cvt + flag zero + bsum + embed ----------------
static constexpr int N_ENC  = 102400;           // 8*200*512/8
static constexpr int N_ENCW = 32768;
static constexpr int N_DECW = 32768;
static constexpr int N_OUTW = 65536;
static constexpr int N_WIH  = 393216;
static constexpr int P0 = N_ENC, P1 = P0+N_ENCW, P2 = P1+N_DECW, P3 = P2+N_OUTW,
                     P4 = P3+N_WIH;   // total 1019904 (=3984*256)
// grid: [0,3984) cvt | [3984,4086) embed | [4086,4089) bsum

__global__ __launch_bounds__(256) void prep_all(const float* __restrict__ enc,
                                                const float* __restrict__ encw,
                                                const float* __restrict__ decw,
                                                const float* __restrict__ outw,
                                                const float* __restrict__ wih,
                                                const float* __restrict__ whh,
                                                const float* __restrict__ emb,
                                                const int* __restrict__ tgt,
                                                const float* __restrict__ bih,
                                                const float* __restrict__ bhh,
                                                unsigned short* __restrict__ d_enc,
                                                unsigned short* __restrict__ d_encw,
                                                unsigned short* __restrict__ d_decw,
                                                unsigned short* __restrict__ d_outw,
                                                unsigned short* __restrict__ d_wih,
                                                unsigned short* __restrict__ d_whh,
                                                unsigned short* __restrict__ x0,
                                                float* __restrict__ bsum,
                                                int* __restrict__ flags) {
  if (blockIdx.x == 0 && threadIdx.x < 97) flags[threadIdx.x * 16] = 0;  // 96 rnn + encdone
  if (blockIdx.x >= 4086) {                    // bsum: 6144 floats, 8/thread
    int i = (blockIdx.x - 4086) * 2048 + threadIdx.x * 8;
#pragma unroll
    for (int k = 0; k < 8; ++k) bsum[i + k] = bih[i + k] + bhh[i + k];
    return;
  }
  if (blockIdx.x >= 3984) {                    // embed: 408*64 threads
    int idx = (blockIdx.x - 3984) * 256 + threadIdx.x;
    if (idx >= MROWS * 64) return;
    int m = idx >> 6, kc = (idx & 63) * 8;
    int t = m >> 3, n = m & 7;
    int v = tgt[n * TO1 + t];
    cvt8(emb + (size_t)v * 512 + kc, x0 + (size_t)m * 512 + kc);
    return;
  }
  int i = blockIdx.x * 256 + threadIdx.x;
  const float* s; unsigned short* d; int rel;
  if      (i < P0) { s = enc;  d = d_enc;  rel = i; }
  else if (i < P1) { s = encw; d = d_encw; rel = i - P0; }
  else if (i < P2) { s = decw; d = d_decw; rel = i - P1; }
  else if (i < P3) { s = outw; d = d_outw; rel = i - P2; }
  else if (i < P4) { s = wih;  d = d_wih;  rel = i - P3; }
  else             { s = whh;  d = d_whh;  rel = i - P4; }
  cvt8(s + (size_t)rel * 8, d + (size_t)rel * 8);
}

// ---------------- joint GEMM: 256x256, 512 thr, BK=64, per-phase interleaved stages ------
// Per K-tile: 4 phases. Phase p issues HALF-TILE p of tile t+1 (2 gll16/thread), phase 0
// waits counted vmcnt(2) (tile t's 8 loads arrived; t+1 h0 in flight), reads B frags
// (phase 0 only, held in VGPRs) + A quadrant p, setprio-wrapped 16 MFMA, barrier.
// This is the m196/m218 lever: staging issuance interleaved with compute, never drain.
__global__ __launch_bounds__(512) void gemm256(const unsigned short* __restrict__ A,
                                               const unsigned short* __restrict__ B,
                                               float* __restrict__ C,
                                               int M, int N, int K) {
  __shared__ __align__(16) unsigned short lds[2][2][16384];   // 128 KB: [buf][A/B][256r x 64k]
  const int tid = threadIdx.x;
  const int wave = tid >> 6, lane = tid & 63;
  const int lr = lane & 15, lg = lane >> 4;
  const int wr = (wave >> 2) * 128;        // 0 / 128
  const int wc = (wave & 3) * 64;          // 0..192

  const int nwg = gridDim.x * gridDim.y;
  const int id = blockIdx.y * gridDim.x + blockIdx.x;
  const int q = nwg >> 3, r = nwg & 7, xcd = id & 7, rest = id >> 3;
  const int nid = (xcd < r ? xcd * (q + 1) : r * (q + 1) + (xcd - r) * q) + rest;
  const size_t n0 = (size_t)(nid % gridDim.x) * 256;
  const size_t m0 = (size_t)(nid / gridDim.x) * 256;

  f32x4 acc[8][4];
#pragma unroll
  for (int i = 0; i < 8; ++i)
#pragma unroll
    for (int j = 0; j < 4; ++j) acc[i][j] = (f32x4){0.f, 0.f, 0.f, 0.f};

  // half-tile h: 0=A rows 0-127, 1=A rows 128-255, 2=B rows 0-127, 3=B rows 128-255.
  // 16 KB each = 2 gll16/thread. Slot swizzle: chunk c stored at slot c^(row&7);
  // linear LDS dest (wave-uniform base + lane*16B), swizzle via global source addr.
#define STGH(bf, kt, h)                                                                 \
  do {                                                                                  \
    const unsigned short* SRC_ = ((h) < 2) ? A : B;                                     \
    const size_t base_ = ((h) < 2) ? m0 : n0;                                           \
    _Pragma("unroll") for (int u = 0; u < 2; ++u) {                                     \
      const int idx2 = u * 512 + tid;                                                   \
      const int rloc = (idx2 >> 3) + (((h) & 1) << 7);                                  \
      const int ch = (idx2 & 7) ^ (rloc & 7);                                           \
      gll16(SRC_ + (base_ + rloc) * (size_t)K + (kt) + ch * 8,                          \
            &lds[bf][(h) >> 1][((((h) & 1) << 10) + u * 512 + wave * 64) * 8]);         \
    }                                                                                   \
  } while (0)

  // prologue: tile 0 fully staged (8 loads in flight)
  STGH(0, 0, 0); STGH(0, 0, 1); STGH(0, 0, 2); STGH(0, 0, 3);

  int cur = 0;
  for (int t = 0; t < 8; ++t) {
    const int nxt = cur ^ 1;
    const unsigned short* As_ = lds[cur][0];
    const unsigned short* Bs_ = lds[cur][1];
    bf16x8 b[4][2];
#pragma unroll
    for (int p = 0; p < 4; ++p) {
      if (t + 1 < 8) STGH(nxt, (t + 1) * 64, p);      // interleaved prefetch issue
      if (p == 0) {
        if (t + 1 < 8) asm volatile("s_waitcnt vmcnt(2)" ::: "memory");  // tile t ready
        else           asm volatile("s_waitcnt vmcnt(0)" ::: "memory");
        __builtin_amdgcn_s_barrier();                 // buf[cur] staged for all waves
#pragma unroll
        for (int j = 0; j < 4; ++j) {
          const int rb = wc + j * 16 + lr;
          const int sw = rb & 7;
          b[j][0] = *(const bf16x8*)&Bs_[rb * 64 + ((lg ^ sw) << 3)];
          b[j][1] = *(const bf16x8*)&Bs_[rb * 64 + (((4 + lg) ^ sw) << 3)];
        }
      }
      bf16x8 a[2][2];
#pragma unroll
      for (int i2 = 0; i2 < 2; ++i2) {
        const int ra = wr + (p * 2 + i2) * 16 + lr;
        const int swa = ra & 7;
        a[i2][0] = *(const bf16x8*)&As_[ra * 64 + ((lg ^ swa) << 3)];
        a[i2][1] = *(const bf16x8*)&As_[ra * 64 + (((4 + lg) ^ swa) << 3)];
      }
      __builtin_amdgcn_s_setprio(1);
#pragma unroll
      for (int i2 = 0; i2 < 2; ++i2) {
        const int i = p * 2 + i2;
#pragma unroll
        for (int j = 0; j < 4; ++j) {
          acc[i][j] = __builtin_amdgcn_mfma_f32_16x16x32_bf16(a[i2][0], b[j][0], acc[i][j], 0, 0, 0);
          acc[i][j] = __builtin_amdgcn_mfma_f32_16x16x32_bf16(a[i2][1], b[j][1], acc[i][j], 0, 0, 0);
        }
      }
      __builtin_amdgcn_s_setprio(0);
      __builtin_amdgcn_s_barrier();                   // phase pacing + buf-reuse guard
    }
    cur = nxt;
  }
#undef STGH

#pragma unroll
  for (int i = 0; i < 8; ++i) {
#pragma unroll
    for (int q2 = 0; q2 < 4; ++q2) {
      const long m = (long)m0 + wr + i * 16 + lg * 4 + q2;
      if (m < M) {
        float* crow = C + (size_t)m * N + n0 + wc;
#pragma unroll
        for (int j = 0; j < 4; ++j) crow[j * 16 + lr] = acc[i][j][q2];
      }
    }
  }
}

// ---------------- mega kernel: rnn(0-95) + enc-proj(96-147) + joint-prep(148-249) --------
// All 250 blocks co-resident (1/CU) -> internal flag pipelining is dispatch-order safe.
__global__ __launch_bounds__(256) void mega_kernel(const unsigned short* __restrict__ wih,
                                                   const unsigned short* __restrict__ whh,
                                                   const float* __restrict__ bsum,
                                                   unsigned short* __restrict__ xtr,
                                                   int* __restrict__ flags,
                                                   const unsigned short* __restrict__ eA,
                                                   const unsigned short* __restrict__ eB,
                                                   float* __restrict__ eC,
                                                   const unsigned short* __restrict__ decw,
                                                   const float* __restrict__ dec_b,
                                                   const float* __restrict__ encp,
                                                   unsigned short* __restrict__ abuf) {
  __shared__ __align__(16) unsigned short w_s[64 * 1024];   // 128 KB (role-dependent alias)
  __shared__ __align__(16) unsigned short x_s[8 * 512];     // 8 KB
  __shared__ __align__(16) unsigned short h_s[8 * 512];     // 8 KB
  __shared__ float gates_s[4][8][16];

  const int tid = threadIdx.x;
  const int wave = tid >> 6, lane = tid & 63;
  const int lr = lane & 15, lg = lane >> 4;
  const int r7 = lr & 7;

  if (blockIdx.x >= 148) {
    // ================= joint-prep workers: dec_p(u,n) + tanh -> abuf =================
    const int wkr = blockIdx.x - 148;          // 0..101
    unsigned short* h3_s = x_s;
    float* decp_row = (float*)w_s;             // 512 floats
    const unsigned short* xtr3 = xtr + 3ull * MROWS * 512;
#pragma unroll 1
    for (int k = 0; k < 4; ++k) {
      const int j = wkr + 102 * k;             // 0..407
      const int u = j >> 3;                    // decoder step
      const int p = j & 7;                     // batch n
      if (wave == 0) {
        for (;;) {
          bool ok = true;
          if (lane < 32) ok = ALOAD(&flags[(64 + lane) * 16]) >= u + 1;
          else if (lane == 32) ok = ALOAD(&flags[96 * 16]) >= 52;
          if (__all(ok)) break;
          __builtin_amdgcn_s_sleep(1);
        }
      }
      __syncthreads();
      {
        const int sr2 = tid >> 5, sc2 = tid & 31;
        const ull* ph = (const ull*)(xtr3 + ((size_t)u * 8 + sr2) * 512);
#pragma unroll
        for (int k2 = 0; k2 < 2; ++k2) {
          const int c_ = sc2 + k2 * 32;
          ull v0 = ALOAD(ph + c_ * 2), v1 = ALOAD(ph + c_ * 2 + 1);
          *(u64x2*)&h3_s[sr2 * 512 + ((c_ ^ sr2) << 3)] = (u64x2){v0, v1};
        }
      }
      __syncthreads();
      {
        const int colbase = wave * 128;
#pragma unroll
        for (int ct = 0; ct < 8; ++ct) {
          f32x4 acc = (f32x4){0.f, 0.f, 0.f, 0.f};
          const int col = colbase + ct * 16 + lr;
#pragma unroll
          for (int c16 = 0; c16 < 16; ++c16) {
            const int cc = c16 * 4 + lg;
            bf16x8 av = *(const bf16x8*)&h3_s[r7 * 512 + ((cc ^ r7) << 3)];
            bf16x8 bv = *(const bf16x8*)&decw[(size_t)col * 512 + cc * 8];
            acc = __builtin_amdgcn_mfma_f32_16x16x32_bf16(av, bv, acc, 0, 0, 0);
          }
#pragma unroll
          for (int q2 = 0; q2 < 4; ++q2)
            if (lg * 4 + q2 == p) decp_row[col] = acc[q2] + dec_b[col];
        }
      }
      __syncthreads();
      {
        const int tr = tid >> 6;               // 0..3 rows per pass
        const int colc = (lane) * 8;           // 0..504
        for (int pass = 0; pass < 50; ++pass) {
          const int nt = p * 200 + pass * 4 + tr;
          const float4v* pe = (const float4v*)(encp + (size_t)nt * 512 + colc);
          float4v e0 = pe[0], e1 = pe[1];
          u16x8 o;
#pragma unroll
          for (int w2 = 0; w2 < 4; ++w2) {
            o[w2]     = f2bf(fast_tanh(e0[w2] + decp_row[colc + w2]));
            o[4 + w2] = f2bf(fast_tanh(e1[w2] + decp_row[colc + 4 + w2]));
          }
          *(u16x8*)&abuf[((size_t)nt * TO1 + u) * 512 + colc] = o;
        }
      }
      __syncthreads();
    }
    return;
  }

  if (blockIdx.x >= 96) {
    // ================= enc-proj GEMM: eC[1664][512] = eA @ eB^T (atomic C) =============
    unsigned short* eld = w_s;
    const int g = blockIdx.x - 96;             // 0..51
    const int wm = (wave >> 1) * 64, wn = (wave & 1) * 64;
    const int xsl = (lg ^ (lr & 3)) << 3;
    const int nwg = 52;
    const int q = nwg >> 3, r = nwg & 7, xcd = g & 7, rest = g >> 3;
    const int nid = (xcd < r ? xcd * (q + 1) : r * (q + 1) + (xcd - r) * q) + rest;
    const size_t n0 = (size_t)(nid & 3) * 128;
    const size_t m0 = (size_t)(nid >> 2) * 128;

    f32x4 acc[4][4];
#pragma unroll
    for (int i = 0; i < 4; ++i)
#pragma unroll
      for (int j = 0; j < 4; ++j) acc[i][j] = (f32x4){0.f, 0.f, 0.f, 0.f};

#define ESTG(bf, kt)                                                                   \
    do {                                                                               \
      _Pragma("unroll") for (int u = 0; u < 2; ++u) {                                  \
        const int s = u * 256 + tid;                                                   \
        const int row_ = s >> 2;                                                       \
        const int ch = (s & 3) ^ (row_ & 3);                                           \
        gll16(eA + (m0 + row_) * 512 + (kt) + ch * 8,                                  \
              &eld[(bf) * 8192 + (u * 256 + wave * 64) * 8]);                          \
      }                                                                                \
      _Pragma("unroll") for (int u = 0; u < 2; ++u) {                                  \
        const int s = u * 256 + tid;                                                   \
        const int row_ = s >> 2;                                                       \
        const int ch = (s & 3) ^ (row_ & 3);                                           \
        gll16(eB + (n0 + row_) * 512 + (kt) + ch * 8,                                  \
              &eld[(bf) * 8192 + 4096 + (u * 256 + wave * 64) * 8]);                   \
      }                                                                                \
    } while (0)

    int cur = 0;
    ESTG(0, 0);
    for (int t = 0; t < 16; ++t) {
      if (t + 1 < 16) {
        ESTG(cur ^ 1, (t + 1) * 32);
        asm volatile("s_waitcnt vmcnt(4)" ::: "memory");
      } else {
        asm volatile("s_waitcnt vmcnt(0)" ::: "memory");
      }
      __builtin_amdgcn_s_barrier();
      const unsigned short* As_ = eld + cur * 8192;
      const unsigned short* Bs_ = As_ + 4096;
      bf16x8 a[4], b[4];
#pragma unroll
      for (int i = 0; i < 4; ++i) a[i] = *(const bf16x8*)&As_[(wm + i * 16 + lr) * 32 + xsl];
#pragma unroll
      for (int j = 0; j < 4; ++j) b[j] = *(const bf16x8*)&Bs_[(wn + j * 16 + lr) * 32 + xsl];
      __builtin_amdgcn_s_setprio(1);
#pragma unroll
      for (int i = 0; i < 4; ++i)
#pragma unroll
        for (int j = 0; j < 4; ++j)
          acc[i][j] = __builtin_amdgcn_mfma_f32_16x16x32_bf16(a[i], b[j], acc[i][j], 0, 0, 0);
      __builtin_amdgcn_s_setprio(0);
      __builtin_amdgcn_s_barrier();
      cur ^= 1;
    }
#undef ESTG

    const int rq = lg * 4;
#pragma unroll
    for (int j = 0; j < 4; ++j) {
      const int col = (int)n0 + wn + j * 16 + lr;
#pragma unroll
      for (int i = 0; i < 4; ++i) {
#pragma unroll
        for (int q2 = 0; q2 < 4; ++q2) {
          const long m = (long)m0 + wm + i * 16 + rq + q2;
          ASTORE(&eC[(size_t)m * 512 + col], acc[i][j][q2]);   // write-through
        }
      }
    }
    asm volatile("s_waitcnt vmcnt(0)" ::: "memory");   // C at coherence point
    __syncthreads();
    if (tid == 0)
      __hip_atomic_fetch_add(&flags[96 * 16], 1, __ATOMIC_RELAXED, __HIP_MEMORY_SCOPE_AGENT);
    return;
  }

  // ================= rnn (blocks 0..95), combined-poll/stage structure =================
  const int l = blockIdx.x >> 5;
  const int b32 = blockIdx.x & 31;
  const int hid0 = b32 << 4;
  const int rw = wave * 16 + lr;

  {
    const int rl = tid >> 2;
    const int qt = tid & 3;
    const size_t R = (size_t)l * 2048 + (size_t)(rl >> 4) * 512 + hid0 + (rl & 15);
    const unsigned short* s0 = wih + R * 512;
    const unsigned short* s1 = whh + R * 512;
#pragma unroll
    for (int i = 0; i < 32; ++i) {
      int c = qt * 32 + i;
      bf16x8 wv = (c < 64) ? *(const bf16x8*)&s0[c * 8] : *(const bf16x8*)&s1[(c - 64) * 8];
      *(bf16x8*)&w_s[rl * 1024 + ((c ^ (rl & 7)) << 3)] = wv;
    }
  }
  const float bias = bsum[(size_t)l * 2048 + (size_t)wave * 512 + hid0 + lr];

  const unsigned short* xin = xtr + (size_t)l * MROWS * 512;
  unsigned short* xout = xtr + (size_t)(l + 1) * MROWS * 512;
  float c_reg = 0.f;
  const int srow = tid >> 5;
  const int sc = tid & 31;
  __syncthreads();

  f32x4 ax0, ax1;

  // ---- prologue: x(0) ----
  if (l > 0) {
    if (wave == 0) {
      for (;;) {
        bool ok_ = true;
        if (lane < 32)
          ok_ = ALOAD(&flags[((l - 1) * 32 + lane) * 16]) >= 1;
        if (__all(ok_)) break;
        __builtin_amdgcn_s_sleep(1);
      }
    }
  }
  __syncthreads();
  {
    const ull* px = (const ull*)(xin + (size_t)srow * 512);
#pragma unroll
    for (int k_ = 0; k_ < 2; ++k_) {
      const int c_ = sc + k_ * 32;
      ull v0 = ALOAD(px + c_ * 2), v1 = ALOAD(px + c_ * 2 + 1);
      *(u64x2*)&x_s[srow * 512 + ((c_ ^ srow) << 3)] = (u64x2){v0, v1};
    }
  }
  __syncthreads();
  ax0 = (f32x4){0.f, 0.f, 0.f, 0.f};
  ax1 = (f32x4){0.f, 0.f, 0.f, 0.f};
#pragma unroll
  for (int c16 = 0; c16 < 16; ++c16) {
    const int cc = c16 * 4 + lg;
    bf16x8 av = *(const bf16x8*)&x_s[r7 * 512 + ((cc ^ r7) << 3)];
    bf16x8 bv = *(const bf16x8*)&w_s[rw * 1024 + ((cc ^ r7) << 3)];
    if (c16 & 1) ax1 = __builtin_amdgcn_mfma_f32_16x16x32_bf16(av, bv, ax1, 0, 0, 0);
    else         ax0 = __builtin_amdgcn_mfma_f32_16x16x32_bf16(av, bv, ax0, 0, 0, 0);
  }

  for (int t = 0; t < TO1; ++t) {
    const bool doH = (t > 0);
    const bool doX = (t + 1 < TO1);
    if (doH || (doX && l > 0)) {
      if (wave == 0) {
        for (;;) {
          bool ok_ = true;
          if (lane < 32) {
            if (doH) ok_ = ALOAD(&flags[(l * 32 + lane) * 16]) >= t;
          } else {
            if (doX && l > 0)
              ok_ = ALOAD(&flags[((l - 1) * 32 + (lane - 32)) * 16]) >= t + 2;
          }
          if (__all(ok_)) break;
          __builtin_amdgcn_s_sleep(1);
        }
      }
    }
    __syncthreads();   // also protects x_s/h_s reuse (prior compute finished)

    {
      ull vh[4], vx[4];
      const ull* ph = (const ull*)(xout + ((size_t)(t - 1) * 8 + srow) * 512);
      const ull* px = (const ull*)(xin + ((size_t)(t + 1) * 8 + srow) * 512);
#pragma unroll
      for (int k_ = 0; k_ < 2; ++k_) {
        const int c_ = sc + k_ * 32;
        if (doH) { vh[2 * k_] = ALOAD(ph + c_ * 2); vh[2 * k_ + 1] = ALOAD(ph + c_ * 2 + 1); }
        if (doX) { vx[2 * k_] = ALOAD(px + c_ * 2); vx[2 * k_ + 1] = ALOAD(px + c_ * 2 + 1); }
      }
#pragma unroll
      for (int k_ = 0; k_ < 2; ++k_) {
        const int c_ = sc + k_ * 32;
        if (doH) *(u64x2*)&h_s[srow * 512 + ((c_ ^ srow) << 3)] = (u64x2){vh[2 * k_], vh[2 * k_ + 1]};
        if (doX) *(u64x2*)&x_s[srow * 512 + ((c_ ^ srow) << 3)] = (u64x2){vx[2 * k_], vx[2 * k_ + 1]};
      }
    }
    __syncthreads();

    f32x4 acc0 = ax0, acc1 = ax1;
    if (doH) {
#pragma unroll
      for (int c16 = 0; c16 < 16; ++c16) {
        const int cc = c16 * 4 + lg;
        bf16x8 av = *(const bf16x8*)&h_s[r7 * 512 + ((cc ^ r7) << 3)];
        bf16x8 bv = *(const bf16x8*)&w_s[rw * 1024 + (((64 + cc) ^ r7) << 3)];
        if (c16 & 1) acc1 = __builtin_amdgcn_mfma_f32_16x16x32_bf16(av, bv, acc1, 0, 0, 0);
        else         acc0 = __builtin_amdgcn_mfma_f32_16x16x32_bf16(av, bv, acc0, 0, 0, 0);
      }
    }

    {
      f32x4 g = acc0 + acc1;
      const int nb4 = lg * 4;
#pragma unroll
      for (int q2 = 0; q2 < 4; ++q2) {
        int n = nb4 + q2;
        if (n < 8) gates_s[wave][n][lr] = g[q2] + bias;
      }
    }
    __syncthreads();
    if (tid < 128) {
      const int n = tid >> 4, j = tid & 15;
      float gi = gates_s[0][n][j], gf = gates_s[1][n][j];
      float gg = gates_s[2][n][j], go = gates_s[3][n][j];
      c_reg = fast_sig(gf) * c_reg + fast_sig(gi) * fast_tanh(gg);
      float ht = fast_sig(go) * fast_tanh(c_reg);
      float htn = __shfl_down(ht, 1);
      if (!(j & 1)) {
        unsigned pk = (unsigned)f2bf(ht) | ((unsigned)f2bf(htn) << 16);
        ASTORE((unsigned*)(xout + ((size_t)t * 8 + n) * 512 + hid0 + j), pk);
      }
    }
    asm volatile("s_waitcnt vmcnt(0)" ::: "memory");   // h at coherence point
    __syncthreads();                                   // ...for ALL waves
    if (tid == 0)
      ASTORE(&flags[(l * 32 + b32) * 16], t + 1);

    if (doX) {
      ax0 = (f32x4){0.f, 0.f, 0.f, 0.f};
      ax1 = (f32x4){0.f, 0.f, 0.f, 0.f};
#pragma unroll
      for (int c16 = 0; c16 < 16; ++c16) {
        const int cc = c16 * 4 + lg;
        bf16x8 av = *(const bf16x8*)&x_s[r7 * 512 + ((cc ^ r7) << 3)];
        bf16x8 bv = *(const bf16x8*)&w_s[rw * 1024 + ((cc ^ r7) << 3)];
        if (c16 & 1) ax1 = __builtin_amdgcn_mfma_f32_16x16x32_bf16(av, bv, ax1, 0, 0, 0);
        else         ax0 = __builtin_amdgcn_mfma_f32_16x16x32_bf16(av, bv, ax0, 0, 0, 0);
      }
    }
  }
}

// ---------------- launch ----------------
extern "C" void kernel_launch(void* const* d_in, const int* in_sizes, int n_in,
                              void* d_out, int out_size, void* d_ws, size_t ws_size,
                              hipStream_t stream) {
  (void)in_sizes; (void)n_in; (void)out_size; (void)ws_size;
  const float* enc_out = (const float*)d_in[0];
  const int*   tgt     = (const int*)d_in[1];
  const float* embed   = (const float*)d_in[2];
  const float* w_ih    = (const float*)d_in[3];
  const float* w_hh    = (const float*)d_in[4];
  const float* b_ih    = (const float*)d_in[5];
  const float* b_hh    = (const float*)d_in[6];
  const float* enc_w   = (const float*)d_in[7];
  const float* dec_w   = (const float*)d_in[8];
  const float* dec_b   = (const float*)d_in[9];
  const float* out_w   = (const float*)d_in[10];

  char* ws = (char*)d_ws;
  unsigned short* enc_bf  = (unsigned short*)(ws + B_ENCBF);
  unsigned short* encw_bf = (unsigned short*)(ws + B_ENCW);
  unsigned short* decw_bf = (unsigned short*)(ws + B_DECW);
  unsigned short* outw_bf = (unsigned short*)(ws + B_OUTW);
  unsigned short* wih_bf  = (unsigned short*)(ws + B_WIH);
  unsigned short* whh_bf  = (unsigned short*)(ws + B_WHH);
  unsigned short* xtr     = (unsigned short*)(ws + B_XTR);
  float* bsum  = (float*)(ws + B_BSUM);
  int*   flags = (int*)(ws + B_FLAGS);
  float* encp  = (float*)(ws + B_ENCP);
  unsigned short* abuf = (unsigned short*)(ws + B_ABUF);
  float* Cout  = (float*)d_out;

  prep_all<<<4089, 256, 0, stream>>>(enc_out, enc_w, dec_w, out_w, w_ih, w_hh,
                                     embed, tgt, b_ih, b_hh,
                                     enc_bf, encw_bf, decw_bf, outw_bf, wih_bf, whh_bf,
                                     xtr, bsum, flags);

  mega_kernel<<<250, 256, 0, stream>>>(wih_bf, whh_bf, bsum, xtr, flags,
                                       enc_bf, encw_bf, encp,
                                       decw_bf, dec_b, encp, abuf);

  gemm256<<<dim3(4, 319), 512, 0, stream>>>(abuf, outw_bf, Cout, MJOINT, VSZ, 512);
}